// Round 4
// baseline (312.929 us; speedup 1.0000x reference)
//
#include <hip/hip_runtime.h>
#include <hip/hip_bf16.h>

#define BATCH 128
#define NPTS  2048
#define NDIM  3
#define NPROJ 100
#define NTH   64    // one wave per block
#define EPT   32    // elements per thread; 64*32 = 2048

// ---------------------------------------------------------------------------
// Exact cross-lane xor shuffle, all on the LDS pipe (VALU is the bottleneck).
// Masks 1..31 -> ds_swizzle bit-mode (xor within 32-lane groups, exact for
// mask<32). Mask 63 -> ds_bpermute with precomputed byte address (wave64).
// ---------------------------------------------------------------------------
template<int M>
__device__ __forceinline__ float shx(float v, int a63) {
  const int x = __float_as_int(v);
  int r;
  if constexpr (M == 63) r = __builtin_amdgcn_ds_bpermute(a63, x);
  else                   r = __builtin_amdgcn_ds_swizzle(x, (M << 10) | 0x1F);
  return __int_as_float(r);
}

// Intra-thread reversal CE: within each group of G slots, pair (r, G-1-r).
// Min always to the lower slot (fixed-direction network).
template<int G>
__device__ __forceinline__ void intra_rev(float v[EPT]) {
#pragma unroll
  for (int g = 0; g < EPT; g += G) {
#pragma unroll
    for (int r = 0; r < G / 2; ++r) {
      const float a = v[g + r], b = v[g + G - 1 - r];
      v[g + r] = fminf(a, b);
      v[g + G - 1 - r] = fmaxf(a, b);
    }
  }
}

// Intra-thread xor CE: pair (s, s|J), min to lower slot.
template<int J>
__device__ __forceinline__ void intra_xor(float v[EPT]) {
#pragma unroll
  for (int s = 0; s < EPT; ++s) {
    if ((s & J) == 0) {
      const float a = v[s], b = v[s | J];
      v[s] = fminf(a, b);
      v[s | J] = fmaxf(a, b);
    }
  }
}

// Cross-lane reversal CE (stage K, W=K/32 threads per block-of-K): partner
// thread tid^M (M=W-1), partner slot 31-s. Upper half (tid&HB, HB=W/2) max.
template<int M, int HB>
__device__ __forceinline__ void cross_rev(float v[EPT], const int tid, const int a63) {
  float o[EPT];
#pragma unroll
  for (int s = 0; s < EPT; ++s) o[s] = shx<M>(v[31 - s], a63);
  if (tid & HB) {
#pragma unroll
    for (int s = 0; s < EPT; ++s) v[s] = fmaxf(v[s], o[s]);
  } else {
#pragma unroll
    for (int s = 0; s < EPT; ++s) v[s] = fminf(v[s], o[s]);
  }
}

// Cross-lane xor CE at thread-stride D: min to lower thread (fixed dir).
template<int D>
__device__ __forceinline__ void cross_xor(float v[EPT], const int tid, const int a63) {
  float o[EPT];
#pragma unroll
  for (int s = 0; s < EPT; ++s) o[s] = shx<D>(v[s], a63);
  if (tid & D) {
#pragma unroll
    for (int s = 0; s < EPT; ++s) v[s] = fmaxf(v[s], o[s]);
  } else {
#pragma unroll
    for (int s = 0; s < EPT; ++s) v[s] = fminf(v[s], o[s]);
  }
}

#define IR(G)     intra_rev<G>(vp); intra_rev<G>(vq)
#define IX(J)     intra_xor<J>(vp); intra_xor<J>(vq)
#define CRV(M,HB) cross_rev<M,HB>(vp, tid, a63); cross_rev<M,HB>(vq, tid, a63)
#define CXR(D)    cross_xor<D>(vp, tid, a63); cross_xor<D>(vq, tid, a63)

// ---------------------------------------------------------------------------
// One 64-thread block per (b, l) pair. Project, fixed-direction register
// bitonic sort (no LDS, no barriers), write one partial SSD per block.
// ---------------------------------------------------------------------------
__global__ __launch_bounds__(NTH, 4) void swd_sort_kernel(
    const float* __restrict__ P, const float* __restrict__ Q,
    const float* __restrict__ proj, float* __restrict__ partial) {
  const int blk = blockIdx.x;  // b * NPROJ + l
  const int b = blk / NPROJ;
  const int l = blk - b * NPROJ;
  const int tid = threadIdx.x;          // 0..63, one full wave
  const int a63 = ((tid ^ 63) << 2);

  const float d0 = proj[b * NDIM * NPROJ + l];
  const float d1 = proj[b * NDIM * NPROJ + NPROJ + l];
  const float d2 = proj[b * NDIM * NPROJ + 2 * NPROJ + l];

  float vp[EPT], vq[EPT];
  const float4* Pb = reinterpret_cast<const float4*>(P + (size_t)b * NPTS * NDIM) + tid * 24;
  const float4* Qb = reinterpret_cast<const float4*>(Q + (size_t)b * NPTS * NDIM) + tid * 24;
#pragma unroll
  for (int c = 0; c < 8; ++c) {  // 3 float4 = 4 points = 4 slots
    const float4 x = Pb[c * 3 + 0], y = Pb[c * 3 + 1], z = Pb[c * 3 + 2];
    vp[c * 4 + 0] = x.x * d0 + x.y * d1 + x.z * d2;
    vp[c * 4 + 1] = x.w * d0 + y.x * d1 + y.y * d2;
    vp[c * 4 + 2] = y.z * d0 + y.w * d1 + z.x * d2;
    vp[c * 4 + 3] = z.y * d0 + z.z * d1 + z.w * d2;
  }
#pragma unroll
  for (int c = 0; c < 8; ++c) {
    const float4 x = Qb[c * 3 + 0], y = Qb[c * 3 + 1], z = Qb[c * 3 + 2];
    vq[c * 4 + 0] = x.x * d0 + x.y * d1 + x.z * d2;
    vq[c * 4 + 1] = x.w * d0 + y.x * d1 + y.y * d2;
    vq[c * 4 + 2] = y.z * d0 + y.w * d1 + z.x * d2;
    vq[c * 4 + 3] = z.y * d0 + z.z * d1 + z.w * d2;
  }

  // ---- fixed-direction bitonic sort of 2048 (layout i = tid*32 + s) ----
  // local: each thread builds an ascending run of 32
  IR(2);
  IR(4);  IX(1);
  IR(8);  IX(2); IX(1);
  IR(16); IX(4); IX(2); IX(1);
  IR(32); IX(8); IX(4); IX(2); IX(1);
  // K=64
  CRV(1, 1);   IX(16); IX(8); IX(4); IX(2); IX(1);
  // K=128
  CRV(3, 2);   CXR(1); IX(16); IX(8); IX(4); IX(2); IX(1);
  // K=256
  CRV(7, 4);   CXR(2); CXR(1); IX(16); IX(8); IX(4); IX(2); IX(1);
  // K=512
  CRV(15, 8);  CXR(4); CXR(2); CXR(1); IX(16); IX(8); IX(4); IX(2); IX(1);
  // K=1024
  CRV(31, 16); CXR(8); CXR(4); CXR(2); CXR(1); IX(16); IX(8); IX(4); IX(2); IX(1);
  // K=2048
  CRV(63, 32); CXR(16); CXR(8); CXR(4); CXR(2); CXR(1); IX(16); IX(8); IX(4); IX(2); IX(1);

  // ---- SSD of sorted arrays ----
  float acc = 0.f;
#pragma unroll
  for (int s = 0; s < EPT; ++s) {
    const float d = vp[s] - vq[s];
    acc += d * d;
  }
#pragma unroll
  for (int off = 32; off > 0; off >>= 1) acc += __shfl_down(acc, off, 64);
  if (tid == 0) partial[blk] = acc;
}

// Single block: per-batch reduce over L partials, sqrt, mean over B.
__global__ __launch_bounds__(BATCH) void swd_finalize_kernel(
    const float* __restrict__ partial, float* __restrict__ out) {
  const int b = threadIdx.x;  // 0..127
  float s = 0.f;
  for (int l = 0; l < NPROJ; ++l) s += partial[b * NPROJ + l];
  float swd = sqrtf(s / (float)(NPTS * NPROJ));
  for (int off = 32; off > 0; off >>= 1) swd += __shfl_down(swd, off, 64);
  __shared__ float wsum[BATCH / 64];
  if ((threadIdx.x & 63) == 0) wsum[threadIdx.x >> 6] = swd;
  __syncthreads();
  if (threadIdx.x == 0) out[0] = (wsum[0] + wsum[1]) / (float)BATCH;
}

extern "C" void kernel_launch(void* const* d_in, const int* in_sizes, int n_in,
                              void* d_out, int out_size, void* d_ws, size_t ws_size,
                              hipStream_t stream) {
  const float* P    = (const float*)d_in[0];
  const float* Q    = (const float*)d_in[1];
  const float* proj = (const float*)d_in[2];
  float* out = (float*)d_out;
  float* partial = (float*)d_ws;  // BATCH*NPROJ floats = 51.2 KB

  swd_sort_kernel<<<BATCH * NPROJ, NTH, 0, stream>>>(P, Q, proj, partial);
  swd_finalize_kernel<<<1, BATCH, 0, stream>>>(partial, out);
}

// Round 5
// 236.537 us; speedup vs baseline: 1.3230x; 1.3230x over previous
//
#include <hip/hip_runtime.h>
#include <hip/hip_bf16.h>

#define BATCH 128
#define NPTS  2048
#define NDIM  3
#define NPROJ 100
#define NTH   64    // one wave per block
#define EPT   32    // elements per thread; 64*32 = 2048

// ---------------------------------------------------------------------------
// Exact cross-lane xor shuffle, all on the LDS pipe (VALU is the bottleneck).
// Masks 1..31 -> ds_swizzle bit-mode (xor within 32-lane groups, exact for
// mask<32). Mask 63 -> ds_bpermute with precomputed byte address (wave64).
// ---------------------------------------------------------------------------
template<int M>
__device__ __forceinline__ float shx(float v, int a63) {
  const int x = __float_as_int(v);
  int r;
  if constexpr (M == 63) r = __builtin_amdgcn_ds_bpermute(a63, x);
  else                   r = __builtin_amdgcn_ds_swizzle(x, (M << 10) | 0x1F);
  return __int_as_float(r);
}

// Intra-thread reversal CE: within each group of G slots, pair (r, G-1-r).
// Min always to the lower slot (fixed-direction network).
template<int G>
__device__ __forceinline__ void intra_rev(float v[EPT]) {
#pragma unroll
  for (int g = 0; g < EPT; g += G) {
#pragma unroll
    for (int r = 0; r < G / 2; ++r) {
      const float a = v[g + r], b = v[g + G - 1 - r];
      v[g + r] = fminf(a, b);
      v[g + G - 1 - r] = fmaxf(a, b);
    }
  }
}

// Intra-thread xor CE: pair (s, s|J), min to lower slot.
template<int J>
__device__ __forceinline__ void intra_xor(float v[EPT]) {
#pragma unroll
  for (int s = 0; s < EPT; ++s) {
    if ((s & J) == 0) {
      const float a = v[s], b = v[s | J];
      v[s] = fminf(a, b);
      v[s | J] = fmaxf(a, b);
    }
  }
}

// Cross-lane reversal CE (stage K): partner thread tid^M, partner slot 31-s.
// Chunked by symmetric slot pairs (s, 31-s), 8 pairs per chunk, so the
// shuffle temp live range is 16 regs and all reads use original values.
template<int M, int HB>
__device__ __forceinline__ void cross_rev(float v[EPT], const int tid, const int a63) {
  const bool up = (tid & HB);
#pragma unroll
  for (int half = 0; half < 2; ++half) {
    float o[16];
#pragma unroll
    for (int r = 0; r < 8; ++r) {
      const int s = half * 8 + r;        // 0..15
      o[r]     = shx<M>(v[31 - s], a63); // partner value for slot s
      o[8 + r] = shx<M>(v[s], a63);      // partner value for slot 31-s
    }
    if (up) {
#pragma unroll
      for (int r = 0; r < 8; ++r) {
        const int s = half * 8 + r;
        v[s]      = fmaxf(v[s], o[r]);
        v[31 - s] = fmaxf(v[31 - s], o[8 + r]);
      }
    } else {
#pragma unroll
      for (int r = 0; r < 8; ++r) {
        const int s = half * 8 + r;
        v[s]      = fminf(v[s], o[r]);
        v[31 - s] = fminf(v[31 - s], o[8 + r]);
      }
    }
  }
}

// Cross-lane xor CE at thread-stride D: min to lower thread (fixed dir).
// Element-local, chunked in 16s to bound live range.
template<int D>
__device__ __forceinline__ void cross_xor(float v[EPT], const int tid, const int a63) {
  const bool up = (tid & D);
#pragma unroll
  for (int half = 0; half < 2; ++half) {
    float o[16];
#pragma unroll
    for (int r = 0; r < 16; ++r) o[r] = shx<D>(v[half * 16 + r], a63);
    if (up) {
#pragma unroll
      for (int r = 0; r < 16; ++r) v[half * 16 + r] = fmaxf(v[half * 16 + r], o[r]);
    } else {
#pragma unroll
      for (int r = 0; r < 16; ++r) v[half * 16 + r] = fminf(v[half * 16 + r], o[r]);
    }
  }
}

#define IR(G)     intra_rev<G>(vp); intra_rev<G>(vq)
#define IX(J)     intra_xor<J>(vp); intra_xor<J>(vq)
#define CRV(M,HB) cross_rev<M,HB>(vp, tid, a63); cross_rev<M,HB>(vq, tid, a63)
#define CXR(D)    cross_xor<D>(vp, tid, a63); cross_xor<D>(vq, tid, a63)

// ---------------------------------------------------------------------------
// One 64-thread block per (b, l) pair. Project, fixed-direction register
// bitonic sort (no LDS, no barriers), write one partial SSD per block.
// ---------------------------------------------------------------------------
__global__ __launch_bounds__(NTH) void swd_sort_kernel(
    const float* __restrict__ P, const float* __restrict__ Q,
    const float* __restrict__ proj, float* __restrict__ partial) {
  const int blk = blockIdx.x;  // b * NPROJ + l
  const int b = blk / NPROJ;
  const int l = blk - b * NPROJ;
  const int tid = threadIdx.x;          // 0..63, one full wave
  const int a63 = ((tid ^ 63) << 2);

  const float d0 = proj[b * NDIM * NPROJ + l];
  const float d1 = proj[b * NDIM * NPROJ + NPROJ + l];
  const float d2 = proj[b * NDIM * NPROJ + 2 * NPROJ + l];

  float vp[EPT], vq[EPT];
  const float4* Pb = reinterpret_cast<const float4*>(P + (size_t)b * NPTS * NDIM) + tid * 24;
  const float4* Qb = reinterpret_cast<const float4*>(Q + (size_t)b * NPTS * NDIM) + tid * 24;
#pragma unroll
  for (int c = 0; c < 8; ++c) {  // 3 float4 = 4 points = 4 slots
    const float4 x = Pb[c * 3 + 0], y = Pb[c * 3 + 1], z = Pb[c * 3 + 2];
    vp[c * 4 + 0] = x.x * d0 + x.y * d1 + x.z * d2;
    vp[c * 4 + 1] = x.w * d0 + y.x * d1 + y.y * d2;
    vp[c * 4 + 2] = y.z * d0 + y.w * d1 + z.x * d2;
    vp[c * 4 + 3] = z.y * d0 + z.z * d1 + z.w * d2;
  }
#pragma unroll
  for (int c = 0; c < 8; ++c) {
    const float4 x = Qb[c * 3 + 0], y = Qb[c * 3 + 1], z = Qb[c * 3 + 2];
    vq[c * 4 + 0] = x.x * d0 + x.y * d1 + x.z * d2;
    vq[c * 4 + 1] = x.w * d0 + y.x * d1 + y.y * d2;
    vq[c * 4 + 2] = y.z * d0 + y.w * d1 + z.x * d2;
    vq[c * 4 + 3] = z.y * d0 + z.z * d1 + z.w * d2;
  }

  // ---- fixed-direction bitonic sort of 2048 (layout i = tid*32 + s) ----
  // local: each thread builds an ascending run of 32
  IR(2);
  IR(4);  IX(1);
  IR(8);  IX(2); IX(1);
  IR(16); IX(4); IX(2); IX(1);
  IR(32); IX(8); IX(4); IX(2); IX(1);
  // K=64
  CRV(1, 1);   IX(16); IX(8); IX(4); IX(2); IX(1);
  // K=128
  CRV(3, 2);   CXR(1); IX(16); IX(8); IX(4); IX(2); IX(1);
  // K=256
  CRV(7, 4);   CXR(2); CXR(1); IX(16); IX(8); IX(4); IX(2); IX(1);
  // K=512
  CRV(15, 8);  CXR(4); CXR(2); CXR(1); IX(16); IX(8); IX(4); IX(2); IX(1);
  // K=1024
  CRV(31, 16); CXR(8); CXR(4); CXR(2); CXR(1); IX(16); IX(8); IX(4); IX(2); IX(1);
  // K=2048
  CRV(63, 32); CXR(16); CXR(8); CXR(4); CXR(2); CXR(1); IX(16); IX(8); IX(4); IX(2); IX(1);

  // ---- SSD of sorted arrays ----
  float acc = 0.f;
#pragma unroll
  for (int s = 0; s < EPT; ++s) {
    const float d = vp[s] - vq[s];
    acc += d * d;
  }
#pragma unroll
  for (int off = 32; off > 0; off >>= 1) acc += __shfl_down(acc, off, 64);
  if (tid == 0) partial[blk] = acc;
}

// Single block: per-batch reduce over L partials, sqrt, mean over B.
__global__ __launch_bounds__(BATCH) void swd_finalize_kernel(
    const float* __restrict__ partial, float* __restrict__ out) {
  const int b = threadIdx.x;  // 0..127
  float s = 0.f;
  for (int l = 0; l < NPROJ; ++l) s += partial[b * NPROJ + l];
  float swd = sqrtf(s / (float)(NPTS * NPROJ));
  for (int off = 32; off > 0; off >>= 1) swd += __shfl_down(swd, off, 64);
  __shared__ float wsum[BATCH / 64];
  if ((threadIdx.x & 63) == 0) wsum[threadIdx.x >> 6] = swd;
  __syncthreads();
  if (threadIdx.x == 0) out[0] = (wsum[0] + wsum[1]) / (float)BATCH;
}

extern "C" void kernel_launch(void* const* d_in, const int* in_sizes, int n_in,
                              void* d_out, int out_size, void* d_ws, size_t ws_size,
                              hipStream_t stream) {
  const float* P    = (const float*)d_in[0];
  const float* Q    = (const float*)d_in[1];
  const float* proj = (const float*)d_in[2];
  float* out = (float*)d_out;
  float* partial = (float*)d_ws;  // BATCH*NPROJ floats = 51.2 KB

  swd_sort_kernel<<<BATCH * NPROJ, NTH, 0, stream>>>(P, Q, proj, partial);
  swd_finalize_kernel<<<1, BATCH, 0, stream>>>(partial, out);
}